// Round 4
// baseline (378.273 us; speedup 1.0000x reference)
//
#include <hip/hip_runtime.h>
#include <hip/hip_bf16.h>
#include <stdint.h>

typedef unsigned short ushort_t;
typedef __attribute__((ext_vector_type(8))) short bf16x8;
typedef __attribute__((ext_vector_type(4))) float f32x4;

__device__ __forceinline__ ushort_t f2bf(float f) {
    uint32_t u = __builtin_bit_cast(uint32_t, f);
    u += 0x7FFF + ((u >> 16) & 1);   // RNE
    return (ushort_t)(u >> 16);
}
__device__ __forceinline__ float bf2f(ushort_t h) {
    return __builtin_bit_cast(float, (uint32_t)h << 16);
}

__device__ __forceinline__ f32x4 mfma16(bf16x8 a, bf16x8 b, f32x4 c) {
    return __builtin_amdgcn_mfma_f32_16x16x32_bf16(a, b, c, 0, 0, 0);
}

#define GLL(g, l) __builtin_amdgcn_global_load_lds(                              \
    (const __attribute__((address_space(1))) void*)(g),                          \
    (__attribute__((address_space(3))) void*)(l), 16, 0, 0)

#define CFENCE asm volatile("" ::: "memory")
#define BARRIER do { CFENCE; __builtin_amdgcn_s_barrier(); CFENCE; } while (0)
#define PRIO1 __builtin_amdgcn_s_setprio(1)
#define PRIO0 __builtin_amdgcn_s_setprio(0)
// barrier, then drain LDS reads, then fence the scheduler (rule #18)
#define PH_SYNC do { BARRIER;                                                    \
    asm volatile("s_waitcnt lgkmcnt(0)" ::: "memory");                           \
    __builtin_amdgcn_sched_barrier(0); } while (0)

// ---------------- fused conversion kernel ----------------

__device__ __forceinline__ void cvt8(const float* s, ushort_t* d) {
    float4 a = ((const float4*)s)[0], b = ((const float4*)s)[1];
    union { bf16x8 v; ushort_t u[8]; } o;
    o.u[0] = f2bf(a.x); o.u[1] = f2bf(a.y); o.u[2] = f2bf(a.z); o.u[3] = f2bf(a.w);
    o.u[4] = f2bf(b.x); o.u[5] = f2bf(b.y); o.u[6] = f2bf(b.z); o.u[7] = f2bf(b.w);
    *(bf16x8*)d = o.v;
}

__global__ __launch_bounds__(256) void cvt_all(
    const float* __restrict__ x,
    const float* __restrict__ Wq, const float* __restrict__ Wk,
    const float* __restrict__ Wv, const float* __restrict__ Wo,
    const float* __restrict__ bq, const float* __restrict__ bk,
    const float* __restrict__ bv,
    ushort_t* __restrict__ xb, ushort_t* __restrict__ wqkv,
    float* __restrict__ bqkv)
{
    const int NX = 16384 * 1024 / 8;   // 2097152
    const int NW = 1024 * 1024 / 8;    // 131072
    int i = blockIdx.x * 256 + threadIdx.x;
    if (i < NX) {
        cvt8(x + (size_t)i * 8, xb + (size_t)i * 8);
    } else if (i < NX + 4 * NW) {
        int j = i - NX;
        int w = j >> 17, off = j & (NW - 1);
        const float* s = (w == 0) ? Wq : (w == 1) ? Wk : (w == 2) ? Wv : Wo;
        cvt8(s + (size_t)off * 8, wqkv + (size_t)j * 8);   // wqkv then wo, contiguous
    } else if (i < NX + 4 * NW + 384) {
        int j = i - NX - 4 * NW;       // 0..383 (bq|bk|bv, 128 units each)
        int w2 = j >> 7, off = j & 127;
        const float* s = (w2 == 0) ? bq : (w2 == 1) ? bk : bv;
        ((float4*)(bqkv + j * 8))[0] = ((const float4*)(s + off * 8))[0];
        ((float4*)(bqkv + j * 8))[1] = ((const float4*)(s + off * 8))[1];
    }
}

// ---------------- 8-phase GEMM: C = A (Mx1024) * B^T (Nx1024) + bias ------
// BM=BN=256, BK=64, 8 waves (2M x 4N), per-wave C = 128x64 = acc[8][4].
// LDS: 2 dbufs x {A 2 halves, B 2 halves} of [128][64] each (128 KiB total).
// dbuf0 <-> even K-steps, dbuf1 <-> odd. Per phase: one C-quadrant (16 MFMA)
// + one half-tile staged (2 GLL). vmcnt(4) at phases 4 and 8 only.
// Stage map (iter i): ph1,2: d1.A <- kt 2i+1 ; ph3,4: d0.B <- kt 2i+2 ;
//                     ph5,6: d0.A <- kt 2i+2 ; ph7,8: d1.B <- kt 2i+3.
// Death: A halves die at ph3/ph7 (A-frags reg-hoisted), B halves at ph2/ph6.
// MODE 0: bf16 out, N=3072 QKV-split; MODE 1: fp32 out, N=1024.

#define STG(P, rb, slot, h, kt) {                                                \
    _Pragma("unroll")                                                            \
    for (int j = 0; j < 2; ++j) {                                                \
        int idx = j * 512 + tid; int row = idx >> 3, ch = idx & 7;               \
        GLL(P + (size_t)((rb) + (h) * 128 + row) * 1024 + (kt) * 64              \
              + ((ch ^ (row & 7)) * 8),                                          \
            (char*)(slot) + (size_t)idx * 16);                                   \
    } }

#define LDA4(d, mibase)                                                          \
    _Pragma("unroll")                                                            \
    for (int q = 0; q < 4; ++q)                                                  \
        _Pragma("unroll")                                                        \
        for (int kk = 0; kk < 2; ++kk)                                           \
            a[q][kk] = *(const bf16x8*)&As[(d) * 2 + wm]                         \
                [((mibase) + q) * 1024 + ln * 64 + cho[kk]];

#define LDB2(d, nibase)                                                          \
    _Pragma("unroll")                                                            \
    for (int q = 0; q < 2; ++q)                                                  \
        _Pragma("unroll")                                                        \
        for (int kk = 0; kk < 2; ++kk)                                           \
            bfr[(nibase) + q][kk] = *(const bf16x8*)&Bs[(d) * 2 + bh]            \
                [brow0 + ((nibase) + q) * 1024 + ln * 64 + cho[kk]];

#define MFMA_Q(qm, qn)                                                           \
    _Pragma("unroll")                                                            \
    for (int mi = 0; mi < 4; ++mi)                                               \
        _Pragma("unroll")                                                        \
        for (int nl = 0; nl < 2; ++nl) {                                         \
            acc[(qm)*4+mi][(qn)*2+nl] =                                          \
                mfma16(a[mi][0], bfr[(qn)*2+nl][0], acc[(qm)*4+mi][(qn)*2+nl]);  \
            acc[(qm)*4+mi][(qn)*2+nl] =                                          \
                mfma16(a[mi][1], bfr[(qn)*2+nl][1], acc[(qm)*4+mi][(qn)*2+nl]);  \
        }

template<int MODE>
__global__ __launch_bounds__(512, 2) void gemm8(
    const ushort_t* __restrict__ A, const ushort_t* __restrict__ B,
    const float* __restrict__ bias, void* __restrict__ outp,
    int M, int NTN)
{
    __shared__ ushort_t As[4][128 * 64];   // [dbuf*2 + half], 64 KiB
    __shared__ ushort_t Bs[4][128 * 64];   // 64 KiB

    const int bid = blockIdx.x;
    const int nwg = gridDim.x;             // % 8 == 0
    const int q8 = nwg >> 3;
    const int swz = (bid & 7) * q8 + (bid >> 3);
    const int m0 = (swz / NTN) * 256;
    const int n0 = (swz % NTN) * 256;

    const int tid = threadIdx.x;
    const int wave = tid >> 6, lane = tid & 63;
    const int wm = wave >> 2, wn = wave & 3;   // 2M x 4N
    const int lg = lane >> 4, ln = lane & 15;
    const int bh = wn >> 1;                    // B half for this wave
    const int brow0 = (wn & 1) * 4096;         // local row base in B half
    int cho[2];
    cho[0] = ((0 * 4 + lg) ^ (ln & 7)) * 8;
    cho[1] = ((1 * 4 + lg) ^ (ln & 7)) * 8;

    f32x4 acc[8][4];
#pragma unroll
    for (int i2 = 0; i2 < 8; ++i2)
#pragma unroll
        for (int j2 = 0; j2 < 4; ++j2) acc[i2][j2] = (f32x4){0.f, 0.f, 0.f, 0.f};

    // prologue: kt0 full into d0, kt1's B into d1; vmcnt(4) leaves d1.B in flight
    STG(A, m0, &As[0][0], 0, 0)
    STG(A, m0, &As[1][0], 1, 0)
    STG(B, n0, &Bs[0][0], 0, 0)
    STG(B, n0, &Bs[1][0], 1, 0)
    STG(B, n0, &Bs[2][0], 0, 1)
    STG(B, n0, &Bs[3][0], 1, 1)
    asm volatile("s_waitcnt vmcnt(4)" ::: "memory");
    BARRIER;

    for (int i = 0; i < 8; ++i) {
        const int kA1 = 2 * i + 1;   // -> d1.A (always exists)
        const int kN  = 2 * i + 2;   // -> d0
        const int kN1 = 2 * i + 3;   // -> d1.B
        const bool pf = (i < 7);
        bf16x8 a[4][2], bfr[4][2];

        // ---- ph1: d0, quadrant (0,0) ----
        LDA4(0, 0) LDB2(0, 0)
        STG(A, m0, &As[2][0], 0, kA1)
        PH_SYNC; PRIO1; MFMA_Q(0, 0) PRIO0;
        BARRIER;
        // ---- ph2: d0, quadrant (0,1) ----
        LDB2(0, 2)
        STG(A, m0, &As[3][0], 1, kA1)
        PH_SYNC; PRIO1; MFMA_Q(0, 1) PRIO0;
        BARRIER;
        // ---- ph3: d0, quadrant (1,0) ----
        LDA4(0, 4)
        if (pf) STG(B, n0, &Bs[0][0], 0, kN)
        PH_SYNC; PRIO1; MFMA_Q(1, 0) PRIO0;
        BARRIER;
        // ---- ph4: d0, quadrant (1,1) ----
        if (pf) STG(B, n0, &Bs[1][0], 1, kN)
        PRIO1; MFMA_Q(1, 1) PRIO0;
        if (pf) { asm volatile("s_waitcnt vmcnt(4)" ::: "memory"); }
        else    { asm volatile("s_waitcnt vmcnt(0)" ::: "memory"); }
        BARRIER;
        // ---- ph5: d1, quadrant (0,0) ----
        LDA4(1, 0) LDB2(1, 0)
        if (pf) STG(A, m0, &As[0][0], 0, kN)
        PH_SYNC; PRIO1; MFMA_Q(0, 0) PRIO0;
        BARRIER;
        // ---- ph6: d1, quadrant (0,1) ----
        LDB2(1, 2)
        if (pf) STG(A, m0, &As[1][0], 1, kN)
        PH_SYNC; PRIO1; MFMA_Q(0, 1) PRIO0;
        BARRIER;
        // ---- ph7: d1, quadrant (1,0) ----
        LDA4(1, 4)
        if (pf) STG(B, n0, &Bs[2][0], 0, kN1)
        PH_SYNC; PRIO1; MFMA_Q(1, 0) PRIO0;
        BARRIER;
        // ---- ph8: d1, quadrant (1,1) ----
        if (pf) STG(B, n0, &Bs[3][0], 1, kN1)
        PRIO1; MFMA_Q(1, 1) PRIO0;
        if (pf) { asm volatile("s_waitcnt vmcnt(4)" ::: "memory"); }
        else    { asm volatile("s_waitcnt vmcnt(0)" ::: "memory"); }
        BARRIER;
    }

    // ---- epilogue ----
#pragma unroll
    for (int ni = 0; ni < 4; ++ni) {
        int n = n0 + wn * 64 + ni * 16 + ln;
        float bval = bias[n];
#pragma unroll
        for (int mi = 0; mi < 8; ++mi) {
#pragma unroll
            for (int r = 0; r < 4; ++r) {
                int m = m0 + wm * 128 + mi * 16 + lg * 4 + r;
                float v = acc[mi][ni][r] + bval;
                if (MODE == 0) {
                    int which = n >> 10, col = n & 1023;
                    ((ushort_t*)outp)[(size_t)which * ((size_t)M * 1024)
                                      + (size_t)m * 1024 + col] = f2bf(v);
                } else {
                    ((float*)outp)[(size_t)m * 1024 + n] = v;
                }
            }
        }
    }
}

// ---------------- attention helpers ----------------

__device__ __forceinline__ bf16x8 bias8(const float* __restrict__ b, int off) {
    float4 f0 = *(const float4*)(b + off);
    float4 f1 = *(const float4*)(b + off + 4);
    union { bf16x8 v; ushort_t u[8]; } o;
    o.u[0] = f2bf(f0.x); o.u[1] = f2bf(f0.y); o.u[2] = f2bf(f0.z); o.u[3] = f2bf(f0.w);
    o.u[4] = f2bf(f1.x); o.u[5] = f2bf(f1.y); o.u[6] = f2bf(f1.z); o.u[7] = f2bf(f1.w);
    return o.v;
}

// ---------------- local attention: 4 waves/block, 1 wave per (chunk, head) --

__global__ __launch_bounds__(256) void attn_local(
    const ushort_t* __restrict__ Q, const ushort_t* __restrict__ K,
    const ushort_t* __restrict__ V, ushort_t* __restrict__ S)
{
    const int wave = threadIdx.x >> 6, lane = threadIdx.x & 63;
    const int unit = blockIdx.x * 4 + wave;
    const int h = unit & 15;
    const int c = unit >> 4;
    const int g = lane >> 4, nn = lane & 15;
    __shared__ ushort_t lds_p[4][16 * 16];
    __shared__ ushort_t vt[4][64 * 16];  // vt[d][n] = V[n][d]

    const size_t rowb = (size_t)c * 16;
    size_t aoff = (rowb + nn) * 1024 + h * 64 + g * 8;
    bf16x8 qa0 = *(const bf16x8*)(Q + aoff);
    bf16x8 qa1 = *(const bf16x8*)(Q + aoff + 32);
    bf16x8 kb0 = *(const bf16x8*)(K + aoff);
    bf16x8 kb1 = *(const bf16x8*)(K + aoff + 32);
    f32x4 sc = {0.f, 0.f, 0.f, 0.f};
    sc = mfma16(qa0, kb0, sc);
    sc = mfma16(qa1, kb1, sc);

#pragma unroll
    for (int r = 0; r < 4; ++r) {
        float s = sc[r] * 0.125f;
        float mx = s;
#pragma unroll
        for (int off = 1; off < 16; off <<= 1) mx = fmaxf(mx, __shfl_xor(mx, off, 64));
        float e = __expf(s - mx);
        float sm = e;
#pragma unroll
        for (int off = 1; off < 16; off <<= 1) sm += __shfl_xor(sm, off, 64);
        lds_p[wave][(g * 4 + r) * 16 + nn] = f2bf(e / sm);
    }

#pragma unroll
    for (int it = 0; it < 2; ++it) {
        int u = it * 64 + lane;
        int n = u >> 3, cc = u & 7;
        bf16x8 vv = *(const bf16x8*)(V + (rowb + n) * 1024 + h * 64 + cc * 8);
        union { bf16x8 v; ushort_t u8[8]; } vu; vu.v = vv;
#pragma unroll
        for (int j = 0; j < 8; ++j) vt[wave][(cc * 8 + j) * 16 + n] = vu.u8[j];
    }
    __syncthreads();

    bf16x8 zero8 = {};
    bf16x8 pa = (g < 2) ? *(const bf16x8*)&lds_p[wave][nn * 16 + g * 8] : zero8;
#pragma unroll
    for (int dt = 0; dt < 4; ++dt) {
        bf16x8 vb = (g < 2) ? *(const bf16x8*)&vt[wave][(dt * 16 + nn) * 16 + g * 8] : zero8;
        f32x4 o = mfma16(pa, vb, (f32x4){0.f, 0.f, 0.f, 0.f});
#pragma unroll
        for (int r = 0; r < 4; ++r) {
            size_t orow = rowb + g * 4 + r;
            S[orow * 1024 + h * 64 + dt * 16 + nn] = f2bf(o[r]);
        }
    }
}

// ---------------- atrous attention: 4 waves/block ----------------

__global__ __launch_bounds__(256) void attn_atrous(
    const ushort_t* __restrict__ Q, const ushort_t* __restrict__ K,
    const ushort_t* __restrict__ V,
    const float* __restrict__ bq, const float* __restrict__ bk,
    const float* __restrict__ bv, ushort_t* __restrict__ S)
{
    const int wave = threadIdx.x >> 6, lane = threadIdx.x & 63;
    const int unit = blockIdx.x * 4 + wave;
    const int h = unit & 15;
    const int tmp = unit >> 4;
    const int c = tmp % 86;
    const int sidx = tmp / 86;
    const int b = sidx / 3, dil = sidx % 3;
    const int g = lane >> 4, nn = lane & 15;
    __shared__ ushort_t lds_p[4][16 * 16];
    __shared__ ushort_t vt[4][64 * 16];

    const int dof = h * 64 + g * 8;
    const int p_n = 3 * (c * 16 + nn) + dil;
    bf16x8 qa0, qa1, kb0, kb1;
    if (p_n < 4096) {
        size_t o = ((size_t)b * 4096 + p_n) * 1024 + dof;
        qa0 = *(const bf16x8*)(Q + o);
        qa1 = *(const bf16x8*)(Q + o + 32);
        kb0 = *(const bf16x8*)(K + o);
        kb1 = *(const bf16x8*)(K + o + 32);
    } else {
        qa0 = bias8(bq, dof); qa1 = bias8(bq, dof + 32);
        kb0 = bias8(bk, dof); kb1 = bias8(bk, dof + 32);
    }
    f32x4 sc = {0.f, 0.f, 0.f, 0.f};
    sc = mfma16(qa0, kb0, sc);
    sc = mfma16(qa1, kb1, sc);

#pragma unroll
    for (int r = 0; r < 4; ++r) {
        float s = sc[r] * 0.125f;
        float mx = s;
#pragma unroll
        for (int off = 1; off < 16; off <<= 1) mx = fmaxf(mx, __shfl_xor(mx, off, 64));
        float e = __expf(s - mx);
        float sm = e;
#pragma unroll
        for (int off = 1; off < 16; off <<= 1) sm += __shfl_xor(sm, off, 64);
        lds_p[wave][(g * 4 + r) * 16 + nn] = f2bf(e / sm);
    }

#pragma unroll
    for (int it = 0; it < 2; ++it) {
        int u = it * 64 + lane;
        int n = u >> 3, cc = u & 7;
        int p_v = 3 * (c * 16 + n) + dil;
        bf16x8 vv = (p_v < 4096)
            ? *(const bf16x8*)(V + ((size_t)b * 4096 + p_v) * 1024 + h * 64 + cc * 8)
            : bias8(bv, h * 64 + cc * 8);
        union { bf16x8 v; ushort_t u8[8]; } vu; vu.v = vv;
#pragma unroll
        for (int j = 0; j < 8; ++j) vt[wave][(cc * 8 + j) * 16 + n] = vu.u8[j];
    }
    __syncthreads();

    bf16x8 zero8 = {};
    bf16x8 pa = (g < 2) ? *(const bf16x8*)&lds_p[wave][nn * 16 + g * 8] : zero8;
#pragma unroll
    for (int dt = 0; dt < 4; ++dt) {
        bf16x8 vb = (g < 2) ? *(const bf16x8*)&vt[wave][(dt * 16 + nn) * 16 + g * 8] : zero8;
        f32x4 o = mfma16(pa, vb, (f32x4){0.f, 0.f, 0.f, 0.f});
#pragma unroll
        for (int r = 0; r < 4; ++r) {
            int p_q = 3 * (c * 16 + g * 4 + r) + dil;
            if (p_q < 4096) {
                size_t off = ((size_t)b * 4096 + p_q) * 1024 + h * 64 + dt * 16 + nn;
                S[off] = f2bf(bf2f(S[off]) + o[r]);
            }
        }
    }
}

// ---------------- launch ----------------

extern "C" void kernel_launch(void* const* d_in, const int* in_sizes, int n_in,
                              void* d_out, int out_size, void* d_ws, size_t ws_size,
                              hipStream_t stream)
{
    const float* x  = (const float*)d_in[0];
    const float* Wq = (const float*)d_in[1];
    const float* bq = (const float*)d_in[2];
    const float* Wk = (const float*)d_in[3];
    const float* bk = (const float*)d_in[4];
    const float* Wv = (const float*)d_in[5];
    const float* bv = (const float*)d_in[6];
    const float* Wo = (const float*)d_in[7];
    const float* bo = (const float*)d_in[8];
    float* out = (float*)d_out;

    const size_t NT = 16384;            // total tokens (4 * 4096)
    ushort_t* xb   = (ushort_t*)d_ws;                  // 16M bf16
    ushort_t* wqkv = xb + NT * 1024;                   // 3M bf16 (Wq|Wk|Wv rows)
    ushort_t* wo   = wqkv + 3 * 1024 * 1024;           // 1M bf16 (contiguous after wqkv)
    ushort_t* Qb   = wo + 1024 * 1024;                 // 16M bf16
    ushort_t* Kb   = Qb + NT * 1024;
    ushort_t* Vb   = Kb + NT * 1024;
    ushort_t* Sb   = Vb + NT * 1024;                   // local+atrous sum, bf16
    float*    bqkv = (float*)(Sb + NT * 1024);         // 3072 fp32

    // fused fp32 -> bf16 conversion + bias pack
    const int total_units = 2097152 + 4 * 131072 + 384;
    cvt_all<<<(total_units + 255) / 256, 256, 0, stream>>>(
        x, Wq, Wk, Wv, Wo, bq, bk, bv, xb, wqkv, bqkv);

    // fused QKV projection: (16384x1024) @ (3072x1024)^T ; grid 64*12=768 (%8==0)
    gemm8<0><<<768, 512, 0, stream>>>(xb, wqkv, bqkv, (void*)Qb, (int)NT, 12);

    // attention
    attn_local <<<4096, 256, 0, stream>>>(Qb, Kb, Vb, Sb);
    attn_atrous<<<4128, 256, 0, stream>>>(Qb, Kb, Vb, bq, bk, bv, Sb);

    // output projection: (16384x1024) @ (1024x1024)^T -> fp32 ; grid 64*4=256
    gemm8<1><<<256, 512, 0, stream>>>(Sb, wo, bo, (void*)out, (int)NT, 4);
}

// Round 5
// 348.854 us; speedup vs baseline: 1.0843x; 1.0843x over previous
//
#include <hip/hip_runtime.h>
#include <hip/hip_bf16.h>
#include <stdint.h>

typedef unsigned short ushort_t;
typedef __attribute__((ext_vector_type(8))) short bf16x8;
typedef __attribute__((ext_vector_type(4))) float f32x4;

__device__ __forceinline__ ushort_t f2bf(float f) {
    uint32_t u = __builtin_bit_cast(uint32_t, f);
    u += 0x7FFF + ((u >> 16) & 1);   // RNE
    return (ushort_t)(u >> 16);
}
__device__ __forceinline__ float bf2f(ushort_t h) {
    return __builtin_bit_cast(float, (uint32_t)h << 16);
}

__device__ __forceinline__ f32x4 mfma16(bf16x8 a, bf16x8 b, f32x4 c) {
    return __builtin_amdgcn_mfma_f32_16x16x32_bf16(a, b, c, 0, 0, 0);
}

#define GLL(g, l) __builtin_amdgcn_global_load_lds(                              \
    (const __attribute__((address_space(1))) void*)(g),                          \
    (__attribute__((address_space(3))) void*)(l), 16, 0, 0)

#define CFENCE asm volatile("" ::: "memory")
#define BARRIER do { CFENCE; __builtin_amdgcn_s_barrier(); CFENCE; } while (0)
#define PRIO1 __builtin_amdgcn_s_setprio(1)
#define PRIO0 __builtin_amdgcn_s_setprio(0)
// m201 template: barrier then full LDS drain. NO sched_barrier (m141: pinning kills).
#define PH_SYNC do { BARRIER;                                                    \
    asm volatile("s_waitcnt lgkmcnt(0)" ::: "memory"); } while (0)

// ---------------- fused conversion kernel ----------------

__device__ __forceinline__ void cvt8(const float* s, ushort_t* d) {
    float4 a = ((const float4*)s)[0], b = ((const float4*)s)[1];
    union { bf16x8 v; ushort_t u[8]; } o;
    o.u[0] = f2bf(a.x); o.u[1] = f2bf(a.y); o.u[2] = f2bf(a.z); o.u[3] = f2bf(a.w);
    o.u[4] = f2bf(b.x); o.u[5] = f2bf(b.y); o.u[6] = f2bf(b.z); o.u[7] = f2bf(b.w);
    *(bf16x8*)d = o.v;
}

__global__ __launch_bounds__(256) void cvt_all(
    const float* __restrict__ x,
    const float* __restrict__ Wq, const float* __restrict__ Wk,
    const float* __restrict__ Wv, const float* __restrict__ Wo,
    const float* __restrict__ bq, const float* __restrict__ bk,
    const float* __restrict__ bv,
    ushort_t* __restrict__ xb, ushort_t* __restrict__ wqkv,
    float* __restrict__ bqkv)
{
    const int NX = 16384 * 1024 / 8;   // 2097152
    const int NW = 1024 * 1024 / 8;    // 131072
    int i = blockIdx.x * 256 + threadIdx.x;
    if (i < NX) {
        cvt8(x + (size_t)i * 8, xb + (size_t)i * 8);
    } else if (i < NX + 4 * NW) {
        int j = i - NX;
        int w = j >> 17, off = j & (NW - 1);
        const float* s = (w == 0) ? Wq : (w == 1) ? Wk : (w == 2) ? Wv : Wo;
        cvt8(s + (size_t)off * 8, wqkv + (size_t)j * 8);   // wqkv then wo, contiguous
    } else if (i < NX + 4 * NW + 384) {
        int j = i - NX - 4 * NW;       // 0..383 (bq|bk|bv, 128 units each)
        int w2 = j >> 7, off = j & 127;
        const float* s = (w2 == 0) ? bq : (w2 == 1) ? bk : bv;
        ((float4*)(bqkv + j * 8))[0] = ((const float4*)(s + off * 8))[0];
        ((float4*)(bqkv + j * 8))[1] = ((const float4*)(s + off * 8))[1];
    }
}

// ---------------- 8-phase GEMM: C = A (Mx1024) * B^T (Nx1024) + bias ------
// BM=BN=256, BK=64, 8 waves (2M x 4N), per-wave C = 128x64 = acc[8][4].
// LDS: 2 dbufs x {A 2 halves, B 2 halves} of [128][64] each (128 KiB total).
// Per phase: one C-quadrant (16 MFMA) + one half-tile staged (2 GLL).
// vmcnt(4) at phases 4 and 8 only (ledger-verified; max 12 in flight).
// Stage map (iter i): ph1,2: d1.A <- kt 2i+1 ; ph3,4: d0.B <- kt 2i+2 ;
//                     ph5,6: d0.A <- kt 2i+2 ; ph7,8: d1.B <- kt 2i+3.
// MODE 0: bf16 out, N=3072 QKV-split; MODE 1: fp32 out, N=1024.

#define STG(P, rb, slot, h, kt) {                                                \
    _Pragma("unroll")                                                            \
    for (int j = 0; j < 2; ++j) {                                                \
        int idx = j * 512 + tid; int row = idx >> 3, ch = idx & 7;               \
        GLL(P + (size_t)((rb) + (h) * 128 + row) * 1024 + (kt) * 64              \
              + ((ch ^ (row & 7)) * 8),                                          \
            (char*)(slot) + (size_t)idx * 16);                                   \
    } }

#define LDA4(d, mibase)                                                          \
    _Pragma("unroll")                                                            \
    for (int q = 0; q < 4; ++q)                                                  \
        _Pragma("unroll")                                                        \
        for (int kk = 0; kk < 2; ++kk)                                           \
            a[q][kk] = *(const bf16x8*)&As[(d) * 2 + wm]                         \
                [((mibase) + q) * 1024 + ln * 64 + cho[kk]];

#define LDB2(d, nibase)                                                          \
    _Pragma("unroll")                                                            \
    for (int q = 0; q < 2; ++q)                                                  \
        _Pragma("unroll")                                                        \
        for (int kk = 0; kk < 2; ++kk)                                           \
            bfr[(nibase) + q][kk] = *(const bf16x8*)&Bs[(d) * 2 + bh]            \
                [brow0 + ((nibase) + q) * 1024 + ln * 64 + cho[kk]];

#define MFMA_Q(qm, qn)                                                           \
    _Pragma("unroll")                                                            \
    for (int mi = 0; mi < 4; ++mi)                                               \
        _Pragma("unroll")                                                        \
        for (int nl = 0; nl < 2; ++nl) {                                         \
            acc[(qm)*4+mi][(qn)*2+nl] =                                          \
                mfma16(a[mi][0], bfr[(qn)*2+nl][0], acc[(qm)*4+mi][(qn)*2+nl]);  \
            acc[(qm)*4+mi][(qn)*2+nl] =                                          \
                mfma16(a[mi][1], bfr[(qn)*2+nl][1], acc[(qm)*4+mi][(qn)*2+nl]);  \
        }

template<int MODE>
__global__ __launch_bounds__(512, 2) void gemm8(
    const ushort_t* __restrict__ A, const ushort_t* __restrict__ B,
    const float* __restrict__ bias, void* __restrict__ outp,
    int M, int NTN)
{
    __shared__ ushort_t As[4][128 * 64];   // [dbuf*2 + half], 64 KiB
    __shared__ ushort_t Bs[4][128 * 64];   // 64 KiB

    const int bid = blockIdx.x;
    const int nwg = gridDim.x;             // % 8 == 0
    const int q8 = nwg >> 3;
    const int swz = (bid & 7) * q8 + (bid >> 3);
    const int m0 = (swz / NTN) * 256;
    const int n0 = (swz % NTN) * 256;

    const int tid = threadIdx.x;
    const int wave = tid >> 6, lane = tid & 63;
    const int wm = wave >> 2, wn = wave & 3;   // 2M x 4N
    const int lg = lane >> 4, ln = lane & 15;
    const int bh = wn >> 1;                    // B half for this wave
    const int brow0 = (wn & 1) * 4096;         // local row base in B half
    int cho[2];
    cho[0] = ((0 * 4 + lg) ^ (ln & 7)) * 8;
    cho[1] = ((1 * 4 + lg) ^ (ln & 7)) * 8;

    f32x4 acc[8][4];
#pragma unroll
    for (int i2 = 0; i2 < 8; ++i2)
#pragma unroll
        for (int j2 = 0; j2 < 4; ++j2) acc[i2][j2] = (f32x4){0.f, 0.f, 0.f, 0.f};

    // prologue: kt0 full into d0, kt1's B into d1; vmcnt(4) leaves d1.B in flight
    STG(A, m0, &As[0][0], 0, 0)
    STG(A, m0, &As[1][0], 1, 0)
    STG(B, n0, &Bs[0][0], 0, 0)
    STG(B, n0, &Bs[1][0], 1, 0)
    STG(B, n0, &Bs[2][0], 0, 1)
    STG(B, n0, &Bs[3][0], 1, 1)
    asm volatile("s_waitcnt vmcnt(4)" ::: "memory");
    BARRIER;

    for (int i = 0; i < 8; ++i) {
        const int kA1 = 2 * i + 1;   // -> d1.A (always exists)
        const int kN  = 2 * i + 2;   // -> d0
        const int kN1 = 2 * i + 3;   // -> d1.B
        const bool pf = (i < 7);
        bf16x8 a[4][2], bfr[4][2];

        // ---- ph1: d0, quadrant (0,0) ----
        LDA4(0, 0) LDB2(0, 0)
        STG(A, m0, &As[2][0], 0, kA1)
        PH_SYNC; PRIO1; MFMA_Q(0, 0) PRIO0;
        BARRIER;
        // ---- ph2: d0, quadrant (0,1) ----
        LDB2(0, 2)
        STG(A, m0, &As[3][0], 1, kA1)
        PH_SYNC; PRIO1; MFMA_Q(0, 1) PRIO0;
        BARRIER;
        // ---- ph3: d0, quadrant (1,0) ----
        LDA4(0, 4)
        if (pf) STG(B, n0, &Bs[0][0], 0, kN)
        PH_SYNC; PRIO1; MFMA_Q(1, 0) PRIO0;
        BARRIER;
        // ---- ph4: d0, quadrant (1,1) ----
        if (pf) STG(B, n0, &Bs[1][0], 1, kN)
        PRIO1; MFMA_Q(1, 1) PRIO0;
        if (pf) { asm volatile("s_waitcnt vmcnt(4)" ::: "memory"); }
        else    { asm volatile("s_waitcnt vmcnt(0)" ::: "memory"); }
        BARRIER;
        // ---- ph5: d1, quadrant (0,0) ----
        LDA4(1, 0) LDB2(1, 0)
        if (pf) STG(A, m0, &As[0][0], 0, kN)
        PH_SYNC; PRIO1; MFMA_Q(0, 0) PRIO0;
        BARRIER;
        // ---- ph6: d1, quadrant (0,1) ----
        LDB2(1, 2)
        if (pf) STG(A, m0, &As[1][0], 1, kN)
        PH_SYNC; PRIO1; MFMA_Q(0, 1) PRIO0;
        BARRIER;
        // ---- ph7: d1, quadrant (1,0) ----
        LDA4(1, 4)
        if (pf) STG(B, n0, &Bs[2][0], 0, kN1)
        PH_SYNC; PRIO1; MFMA_Q(1, 0) PRIO0;
        BARRIER;
        // ---- ph8: d1, quadrant (1,1) ----
        if (pf) STG(B, n0, &Bs[3][0], 1, kN1)
        PRIO1; MFMA_Q(1, 1) PRIO0;
        if (pf) { asm volatile("s_waitcnt vmcnt(4)" ::: "memory"); }
        else    { asm volatile("s_waitcnt vmcnt(0)" ::: "memory"); }
        BARRIER;
    }

    // ---- epilogue: mi,r outer / ni inner -> contiguous 128B runs per wave ----
    float bval[4];
#pragma unroll
    for (int ni = 0; ni < 4; ++ni) bval[ni] = bias[n0 + wn * 64 + ni * 16 + ln];

    if (MODE == 0) {
        // which is constant per block (n0 is a multiple of 256; 256 | 1024)
        ushort_t* obase = (ushort_t*)outp + (size_t)(n0 >> 10) * ((size_t)M * 1024)
                          + (n0 & 1023) + wn * 64 + ln;
#pragma unroll
        for (int mi = 0; mi < 8; ++mi) {
#pragma unroll
            for (int r = 0; r < 4; ++r) {
                int m = m0 + wm * 128 + mi * 16 + lg * 4 + r;
                ushort_t* orow = obase + (size_t)m * 1024;
#pragma unroll
                for (int ni = 0; ni < 4; ++ni)
                    orow[ni * 16] = f2bf(acc[mi][ni][r] + bval[ni]);
            }
        }
    } else {
        float* obase = (float*)outp + n0 + wn * 64 + ln;
#pragma unroll
        for (int mi = 0; mi < 8; ++mi) {
#pragma unroll
            for (int r = 0; r < 4; ++r) {
                int m = m0 + wm * 128 + mi * 16 + lg * 4 + r;
                float* orow = obase + (size_t)m * 1024;
#pragma unroll
                for (int ni = 0; ni < 4; ++ni)
                    orow[ni * 16] = acc[mi][ni][r] + bval[ni];
            }
        }
    }
}

// ---------------- attention helpers ----------------

__device__ __forceinline__ bf16x8 bias8(const float* __restrict__ b, int off) {
    float4 f0 = *(const float4*)(b + off);
    float4 f1 = *(const float4*)(b + off + 4);
    union { bf16x8 v; ushort_t u[8]; } o;
    o.u[0] = f2bf(f0.x); o.u[1] = f2bf(f0.y); o.u[2] = f2bf(f0.z); o.u[3] = f2bf(f0.w);
    o.u[4] = f2bf(f1.x); o.u[5] = f2bf(f1.y); o.u[6] = f2bf(f1.z); o.u[7] = f2bf(f1.w);
    return o.v;
}

// ---------------- local attention: 4 waves/block, 1 wave per (chunk, head) --
// Waves are fully independent (per-wave LDS slices) -> no __syncthreads.

__global__ __launch_bounds__(256) void attn_local(
    const ushort_t* __restrict__ Q, const ushort_t* __restrict__ K,
    const ushort_t* __restrict__ V, ushort_t* __restrict__ S)
{
    const int wave = threadIdx.x >> 6, lane = threadIdx.x & 63;
    const int unit = blockIdx.x * 4 + wave;
    const int h = unit & 15;
    const int c = unit >> 4;
    const int g = lane >> 4, nn = lane & 15;
    __shared__ ushort_t lds_p[4][16 * 16];
    __shared__ ushort_t vt[4][64 * 16];  // vt[d][n] = V[n][d]

    const size_t rowb = (size_t)c * 16;
    size_t aoff = (rowb + nn) * 1024 + h * 64 + g * 8;
    bf16x8 qa0 = *(const bf16x8*)(Q + aoff);
    bf16x8 qa1 = *(const bf16x8*)(Q + aoff + 32);
    bf16x8 kb0 = *(const bf16x8*)(K + aoff);
    bf16x8 kb1 = *(const bf16x8*)(K + aoff + 32);

    // V transpose into per-wave LDS slice (independent of other waves)
#pragma unroll
    for (int it = 0; it < 2; ++it) {
        int u = it * 64 + lane;
        int n = u >> 3, cc = u & 7;
        bf16x8 vv = *(const bf16x8*)(V + (rowb + n) * 1024 + h * 64 + cc * 8);
        union { bf16x8 v; ushort_t u8[8]; } vu; vu.v = vv;
#pragma unroll
        for (int j = 0; j < 8; ++j) vt[wave][(cc * 8 + j) * 16 + n] = vu.u8[j];
    }

    f32x4 sc = {0.f, 0.f, 0.f, 0.f};
    sc = mfma16(qa0, kb0, sc);
    sc = mfma16(qa1, kb1, sc);

#pragma unroll
    for (int r = 0; r < 4; ++r) {
        float s = sc[r] * 0.125f;
        float mx = s;
#pragma unroll
        for (int off = 1; off < 16; off <<= 1) mx = fmaxf(mx, __shfl_xor(mx, off, 64));
        float e = __expf(s - mx);
        float sm = e;
#pragma unroll
        for (int off = 1; off < 16; off <<= 1) sm += __shfl_xor(sm, off, 64);
        lds_p[wave][(g * 4 + r) * 16 + nn] = f2bf(e / sm);
    }
    CFENCE;

    bf16x8 zero8 = {};
    bf16x8 pa = (g < 2) ? *(const bf16x8*)&lds_p[wave][nn * 16 + g * 8] : zero8;
#pragma unroll
    for (int dt = 0; dt < 4; ++dt) {
        bf16x8 vb = (g < 2) ? *(const bf16x8*)&vt[wave][(dt * 16 + nn) * 16 + g * 8] : zero8;
        f32x4 o = mfma16(pa, vb, (f32x4){0.f, 0.f, 0.f, 0.f});
#pragma unroll
        for (int r = 0; r < 4; ++r) {
            size_t orow = rowb + g * 4 + r;
            S[orow * 1024 + h * 64 + dt * 16 + nn] = f2bf(o[r]);
        }
    }
}

// ---------------- atrous attention: 4 waves/block, independent waves ------

__global__ __launch_bounds__(256) void attn_atrous(
    const ushort_t* __restrict__ Q, const ushort_t* __restrict__ K,
    const ushort_t* __restrict__ V,
    const float* __restrict__ bq, const float* __restrict__ bk,
    const float* __restrict__ bv, ushort_t* __restrict__ S)
{
    const int wave = threadIdx.x >> 6, lane = threadIdx.x & 63;
    const int unit = blockIdx.x * 4 + wave;
    const int h = unit & 15;
    const int tmp = unit >> 4;
    const int c = tmp % 86;
    const int sidx = tmp / 86;
    const int b = sidx / 3, dil = sidx % 3;
    const int g = lane >> 4, nn = lane & 15;
    __shared__ ushort_t lds_p[4][16 * 16];
    __shared__ ushort_t vt[4][64 * 16];

    const int dof = h * 64 + g * 8;
    const int p_n = 3 * (c * 16 + nn) + dil;
    bf16x8 qa0, qa1, kb0, kb1;
    if (p_n < 4096) {
        size_t o = ((size_t)b * 4096 + p_n) * 1024 + dof;
        qa0 = *(const bf16x8*)(Q + o);
        qa1 = *(const bf16x8*)(Q + o + 32);
        kb0 = *(const bf16x8*)(K + o);
        kb1 = *(const bf16x8*)(K + o + 32);
    } else {
        qa0 = bias8(bq, dof); qa1 = bias8(bq, dof + 32);
        kb0 = bias8(bk, dof); kb1 = bias8(bk, dof + 32);
    }

#pragma unroll
    for (int it = 0; it < 2; ++it) {
        int u = it * 64 + lane;
        int n = u >> 3, cc = u & 7;
        int p_v = 3 * (c * 16 + n) + dil;
        bf16x8 vv = (p_v < 4096)
            ? *(const bf16x8*)(V + ((size_t)b * 4096 + p_v) * 1024 + h * 64 + cc * 8)
            : bias8(bv, h * 64 + cc * 8);
        union { bf16x8 v; ushort_t u8[8]; } vu; vu.v = vv;
#pragma unroll
        for (int j = 0; j < 8; ++j) vt[wave][(cc * 8 + j) * 16 + n] = vu.u8[j];
    }

    f32x4 sc = {0.f, 0.f, 0.f, 0.f};
    sc = mfma16(qa0, kb0, sc);
    sc = mfma16(qa1, kb1, sc);

#pragma unroll
    for (int r = 0; r < 4; ++r) {
        float s = sc[r] * 0.125f;
        float mx = s;
#pragma unroll
        for (int off = 1; off < 16; off <<= 1) mx = fmaxf(mx, __shfl_xor(mx, off, 64));
        float e = __expf(s - mx);
        float sm = e;
#pragma unroll
        for (int off = 1; off < 16; off <<= 1) sm += __shfl_xor(sm, off, 64);
        lds_p[wave][(g * 4 + r) * 16 + nn] = f2bf(e / sm);
    }
    CFENCE;

    bf16x8 zero8 = {};
    bf16x8 pa = (g < 2) ? *(const bf16x8*)&lds_p[wave][nn * 16 + g * 8] : zero8;
#pragma unroll
    for (int dt = 0; dt < 4; ++dt) {
        bf16x8 vb = (g < 2) ? *(const bf16x8*)&vt[wave][(dt * 16 + nn) * 16 + g * 8] : zero8;
        f32x4 o = mfma16(pa, vb, (f32x4){0.f, 0.f, 0.f, 0.f});
#pragma unroll
        for (int r = 0; r < 4; ++r) {
            int p_q = 3 * (c * 16 + g * 4 + r) + dil;
            if (p_q < 4096) {
                size_t off = ((size_t)b * 4096 + p_q) * 1024 + h * 64 + dt * 16 + nn;
                S[off] = f2bf(bf2f(S[off]) + o[r]);
            }
        }
    }
}

// ---------------- launch ----------------

extern "C" void kernel_launch(void* const* d_in, const int* in_sizes, int n_in,
                              void* d_out, int out_size, void* d_ws, size_t ws_size,
                              hipStream_t stream)
{
    const float* x  = (const float*)d_in[0];
    const float* Wq = (const float*)d_in[1];
    const float* bq = (const float*)d_in[2];
    const float* Wk = (const float*)d_in[3];
    const float* bk = (const float*)d_in[4];
    const float* Wv = (const float*)d_in[5];
    const float* bv = (const float*)d_in[6];
    const float* Wo = (const float*)d_in[7];
    const float* bo = (const float*)d_in[8];
    float* out = (float*)d_out;

    const size_t NT = 16384;            // total tokens (4 * 4096)
    ushort_t* xb   = (ushort_t*)d_ws;                  // 16M bf16
    ushort_t* wqkv = xb + NT * 1024;                   // 3M bf16 (Wq|Wk|Wv rows)
    ushort_t* wo   = wqkv + 3 * 1024 * 1024;           // 1M bf16 (contiguous after wqkv)
    ushort_t* Qb   = wo + 1024 * 1024;                 // 16M bf16
    ushort_t* Kb   = Qb + NT * 1024;
    ushort_t* Vb   = Kb + NT * 1024;
    ushort_t* Sb   = Vb + NT * 1024;                   // local+atrous sum, bf16
    float*    bqkv = (float*)(Sb + NT * 1024);         // 3072 fp32

    // fused fp32 -> bf16 conversion + bias pack
    const int total_units = 2097152 + 4 * 131072 + 384;
    cvt_all<<<(total_units + 255) / 256, 256, 0, stream>>>(
        x, Wq, Wk, Wv, Wo, bq, bk, bv, xb, wqkv, bqkv);

    // fused QKV projection: (16384x1024) @ (3072x1024)^T ; grid 64*12=768 (%8==0)
    gemm8<0><<<768, 512, 0, stream>>>(xb, wqkv, bqkv, (void*)Qb, (int)NT, 12);

    // attention
    attn_local <<<4096, 256, 0, stream>>>(Qb, Kb, Vb, Sb);
    attn_atrous<<<4128, 256, 0, stream>>>(Qb, Kb, Vb, bq, bk, bv, Sb);

    // output projection: (16384x1024) @ (1024x1024)^T -> fp32 ; grid 64*4=256
    gemm8<1><<<256, 512, 0, stream>>>(Sb, wo, bo, (void*)out, (int)NT, 4);
}

// Round 6
// 344.908 us; speedup vs baseline: 1.0967x; 1.0114x over previous
//
#include <hip/hip_runtime.h>
#include <hip/hip_bf16.h>
#include <stdint.h>

typedef unsigned short ushort_t;
typedef __attribute__((ext_vector_type(8))) short bf16x8;
typedef __attribute__((ext_vector_type(4))) float f32x4;

__device__ __forceinline__ ushort_t f2bf(float f) {
    uint32_t u = __builtin_bit_cast(uint32_t, f);
    u += 0x7FFF + ((u >> 16) & 1);   // RNE
    return (ushort_t)(u >> 16);
}
__device__ __forceinline__ float bf2f(ushort_t h) {
    return __builtin_bit_cast(float, (uint32_t)h << 16);
}

__device__ __forceinline__ f32x4 mfma16(bf16x8 a, bf16x8 b, f32x4 c) {
    return __builtin_amdgcn_mfma_f32_16x16x32_bf16(a, b, c, 0, 0, 0);
}

#define GLL(g, l) __builtin_amdgcn_global_load_lds(                              \
    (const __attribute__((address_space(1))) void*)(g),                          \
    (__attribute__((address_space(3))) void*)(l), 16, 0, 0)

#define CFENCE asm volatile("" ::: "memory")
#define BARRIER do { CFENCE; __builtin_amdgcn_s_barrier(); CFENCE; } while (0)
#define PRIO1 __builtin_amdgcn_s_setprio(1)
#define PRIO0 __builtin_amdgcn_s_setprio(0)
#define VM4 asm volatile("s_waitcnt vmcnt(4)" ::: "memory")
#define VM0 asm volatile("s_waitcnt vmcnt(0)" ::: "memory")

// ---------------- fused conversion kernel ----------------

__device__ __forceinline__ void cvt8(const float* s, ushort_t* d) {
    float4 a = ((const float4*)s)[0], b = ((const float4*)s)[1];
    union { bf16x8 v; ushort_t u[8]; } o;
    o.u[0] = f2bf(a.x); o.u[1] = f2bf(a.y); o.u[2] = f2bf(a.z); o.u[3] = f2bf(a.w);
    o.u[4] = f2bf(b.x); o.u[5] = f2bf(b.y); o.u[6] = f2bf(b.z); o.u[7] = f2bf(b.w);
    *(bf16x8*)d = o.v;
}

__global__ __launch_bounds__(256) void cvt_all(
    const float* __restrict__ x,
    const float* __restrict__ Wq, const float* __restrict__ Wk,
    const float* __restrict__ Wv, const float* __restrict__ Wo,
    const float* __restrict__ bq, const float* __restrict__ bk,
    const float* __restrict__ bv,
    ushort_t* __restrict__ xb, ushort_t* __restrict__ wqkv,
    float* __restrict__ bqkv)
{
    const int NX = 16384 * 1024 / 8;   // 2097152
    const int NW = 1024 * 1024 / 8;    // 131072
    int i = blockIdx.x * 256 + threadIdx.x;
    if (i < NX) {
        cvt8(x + (size_t)i * 8, xb + (size_t)i * 8);
    } else if (i < NX + 4 * NW) {
        int j = i - NX;
        int w = j >> 17, off = j & (NW - 1);
        const float* s = (w == 0) ? Wq : (w == 1) ? Wk : (w == 2) ? Wv : Wo;
        cvt8(s + (size_t)off * 8, wqkv + (size_t)j * 8);   // wqkv then wo, contiguous
    } else if (i < NX + 4 * NW + 384) {
        int j = i - NX - 4 * NW;       // 0..383 (bq|bk|bv, 128 units each)
        int w2 = j >> 7, off = j & 127;
        const float* s = (w2 == 0) ? bq : (w2 == 1) ? bk : bv;
        ((float4*)(bqkv + j * 8))[0] = ((const float4*)(s + off * 8))[0];
        ((float4*)(bqkv + j * 8))[1] = ((const float4*)(s + off * 8))[1];
    }
}

// ---------------- pipelined GEMM v6: C = A (Mx1024) * B^T (Nx1024) + bias --
// BM=BN=256, BK=32, NK=32 K-tiles. 8 waves (2M x 4N), per-wave C = 128x64.
// 4 LDS buffers (A 16KB + B 16KB each = 128 KiB), stage 3 K-tiles ahead,
// 4 GLL per K-tile (A:2 phA, B:2 phB); boundary vmcnt(4) => kt+2 resident.
// Register-double-buffered operands: each phase issues the NEXT phase's
// ds_reads, then runs 16 MFMA on regs loaded last phase. ONE barrier/K-tile.
// Ledger invariant at start of kt: kt,kt+1 resident; kt+2's 4 GLL in flight.
// MODE 0: bf16 out, N=3072 QKV-split; MODE 1: fp32 out, N=1024.

#define STGA(bq, kt) { _Pragma("unroll")                                         \
    for (int j = 0; j < 2; ++j) {                                                \
        int idx = j * 512 + tid; int row = idx >> 2, ch = idx & 3;               \
        GLL(A + (size_t)(m0 + row) * 1024 + (kt) * 32 + ((ch ^ (row & 3)) * 8),  \
            (char*)&As[bq][0] + (size_t)idx * 16);                               \
    } }
#define STGB(bq, kt) { _Pragma("unroll")                                         \
    for (int j = 0; j < 2; ++j) {                                                \
        int idx = j * 512 + tid; int row = idx >> 2, ch = idx & 3;               \
        GLL(B + (size_t)(n0 + row) * 1024 + (kt) * 32 + ((ch ^ (row & 3)) * 8),  \
            (char*)&Bs[bq][0] + (size_t)idx * 16);                               \
    } }

// A-frag rows: wm*128 + (mibase+q)*16 + ln ; chunk XOR reduces to lg^(ln&3)
#define RD4(dst, bq, mibase) { _Pragma("unroll")                                 \
    for (int q = 0; q < 4; ++q)                                                  \
        dst[q] = *(const bf16x8*)&As[bq][(wm * 128 + ((mibase) + q) * 16 + ln)   \
                                        * 32 + cho]; }
#define RDB(dst, bq) { _Pragma("unroll")                                         \
    for (int q = 0; q < 4; ++q)                                                  \
        dst[q] = *(const bf16x8*)&Bs[bq][(wn * 64 + q * 16 + ln) * 32 + cho]; }

#define MFMA16(mibase, av, bv) { _Pragma("unroll")                               \
    for (int mi = 0; mi < 4; ++mi) _Pragma("unroll")                             \
        for (int ni = 0; ni < 4; ++ni)                                           \
            acc[(mibase) + mi][ni] =                                             \
                mfma16(av[mi], bv[ni], acc[(mibase) + mi][ni]); }

template<int MODE>
__global__ __launch_bounds__(512, 2) void gemm6(
    const ushort_t* __restrict__ A, const ushort_t* __restrict__ B,
    const float* __restrict__ bias, void* __restrict__ outp,
    int M, int NTN)
{
    __shared__ ushort_t As[4][256 * 32];   // 4 x 16 KiB
    __shared__ ushort_t Bs[4][256 * 32];   // 4 x 16 KiB
    const int NK = 32;                     // K = 1024, BK = 32

    const int bid = blockIdx.x;
    const int nwg = gridDim.x;             // % 8 == 0
    const int q8 = nwg >> 3;
    const int swz = (bid & 7) * q8 + (bid >> 3);
    const int m0 = (swz / NTN) * 256;
    const int n0 = (swz % NTN) * 256;

    const int tid = threadIdx.x;
    const int wave = tid >> 6, lane = tid & 63;
    const int wm = wave >> 2, wn = wave & 3;   // 2M x 4N
    const int lg = lane >> 4, ln = lane & 15;
    const int cho = (lg ^ (ln & 3)) * 8;

    f32x4 acc[8][4];
#pragma unroll
    for (int i2 = 0; i2 < 8; ++i2)
#pragma unroll
        for (int j2 = 0; j2 < 4; ++j2) acc[i2][j2] = (f32x4){0.f, 0.f, 0.f, 0.f};

    // prologue: stage kt0,1,2 ; vmcnt(4) -> kt0,kt1 resident, kt2 in flight
    STGA(0, 0) STGB(0, 0)
    STGA(1, 1) STGB(1, 1)
    STGA(2, 2) STGB(2, 2)
    VM4;
    BARRIER;

    bf16x8 aE0[4], aE1[4], aO0[4], aO1[4], bE[4], bO[4];
    RD4(aE0, 0, 0) RDB(bE, 0)          // kt0 first-half operands

    for (int it = 0; it < 16; ++it) {
        const int ke = 2 * it, ko = ke + 1;
        const int ce = (it & 1) << 1, co = ce | 1;
        const int s1 = (ke + 3) & 3;   // buffer for kt ke+3
        const int s2 = ce;             // buffer for kt ko+3 (= ke+4)
        const bool p1 = (ke + 3 < NK), p2 = (ko + 3 < NK);

        // ---- phA (kt=ke, mi 0-3): prefetch ke's 2nd half; MFMA on aE0/bE ----
        RD4(aE1, ce, 4)
        if (p1) STGA(s1, ke + 3)
        PRIO1; MFMA16(0, aE0, bE) PRIO0;

        // ---- phB (kt=ke, mi 4-7): prefetch ko's 1st half + B ----
        RD4(aO0, co, 0) RDB(bO, co)
        if (p1) STGB(s1, ke + 3)
        PRIO1; MFMA16(4, aE1, bE) PRIO0;
        if (p1) { VM4; } else { VM0; }
        BARRIER;

        // ---- phC (kt=ko, mi 0-3): prefetch ko's 2nd half ----
        RD4(aO1, co, 4)
        if (p2) STGA(s2, ko + 3)
        PRIO1; MFMA16(0, aO0, bO) PRIO0;

        // ---- phD (kt=ko, mi 4-7): prefetch (ke+2)'s 1st half + B ----
        if (it + 1 < 16) { RD4(aE0, (ce + 2) & 3, 0) RDB(bE, (ce + 2) & 3) }
        if (p2) STGB(s2, ko + 3)
        PRIO1; MFMA16(4, aO1, bO) PRIO0;
        if (p2) { VM4; } else { VM0; }
        BARRIER;
    }

    // ---- epilogue: mi,r outer / ni inner -> contiguous 128B runs per wave ----
    float bval[4];
#pragma unroll
    for (int ni = 0; ni < 4; ++ni) bval[ni] = bias[n0 + wn * 64 + ni * 16 + ln];

    if (MODE == 0) {
        ushort_t* obase = (ushort_t*)outp + (size_t)(n0 >> 10) * ((size_t)M * 1024)
                          + (n0 & 1023) + wn * 64 + ln;
#pragma unroll
        for (int mi = 0; mi < 8; ++mi) {
#pragma unroll
            for (int r = 0; r < 4; ++r) {
                int m = m0 + wm * 128 + mi * 16 + lg * 4 + r;
                ushort_t* orow = obase + (size_t)m * 1024;
#pragma unroll
                for (int ni = 0; ni < 4; ++ni)
                    orow[ni * 16] = f2bf(acc[mi][ni][r] + bval[ni]);
            }
        }
    } else {
        float* obase = (float*)outp + n0 + wn * 64 + ln;
#pragma unroll
        for (int mi = 0; mi < 8; ++mi) {
#pragma unroll
            for (int r = 0; r < 4; ++r) {
                int m = m0 + wm * 128 + mi * 16 + lg * 4 + r;
                float* orow = obase + (size_t)m * 1024;
#pragma unroll
                for (int ni = 0; ni < 4; ++ni)
                    orow[ni * 16] = acc[mi][ni][r] + bval[ni];
            }
        }
    }
}

// ---------------- attention helpers ----------------

__device__ __forceinline__ bf16x8 bias8(const float* __restrict__ b, int off) {
    float4 f0 = *(const float4*)(b + off);
    float4 f1 = *(const float4*)(b + off + 4);
    union { bf16x8 v; ushort_t u[8]; } o;
    o.u[0] = f2bf(f0.x); o.u[1] = f2bf(f0.y); o.u[2] = f2bf(f0.z); o.u[3] = f2bf(f0.w);
    o.u[4] = f2bf(f1.x); o.u[5] = f2bf(f1.y); o.u[6] = f2bf(f1.z); o.u[7] = f2bf(f1.w);
    return o.v;
}

// ---------------- local attention: 4 waves/block, 1 wave per (chunk, head) --
// Waves are fully independent (per-wave LDS slices) -> no __syncthreads.

__global__ __launch_bounds__(256) void attn_local(
    const ushort_t* __restrict__ Q, const ushort_t* __restrict__ K,
    const ushort_t* __restrict__ V, ushort_t* __restrict__ S)
{
    const int wave = threadIdx.x >> 6, lane = threadIdx.x & 63;
    const int unit = blockIdx.x * 4 + wave;
    const int h = unit & 15;
    const int c = unit >> 4;
    const int g = lane >> 4, nn = lane & 15;
    __shared__ ushort_t lds_p[4][16 * 16];
    __shared__ ushort_t vt[4][64 * 16];  // vt[d][n] = V[n][d]

    const size_t rowb = (size_t)c * 16;
    size_t aoff = (rowb + nn) * 1024 + h * 64 + g * 8;
    bf16x8 qa0 = *(const bf16x8*)(Q + aoff);
    bf16x8 qa1 = *(const bf16x8*)(Q + aoff + 32);
    bf16x8 kb0 = *(const bf16x8*)(K + aoff);
    bf16x8 kb1 = *(const bf16x8*)(K + aoff + 32);

    // V transpose into per-wave LDS slice (independent of other waves)
#pragma unroll
    for (int it = 0; it < 2; ++it) {
        int u = it * 64 + lane;
        int n = u >> 3, cc = u & 7;
        bf16x8 vv = *(const bf16x8*)(V + (rowb + n) * 1024 + h * 64 + cc * 8);
        union { bf16x8 v; ushort_t u8[8]; } vu; vu.v = vv;
#pragma unroll
        for (int j = 0; j < 8; ++j) vt[wave][(cc * 8 + j) * 16 + n] = vu.u8[j];
    }

    f32x4 sc = {0.f, 0.f, 0.f, 0.f};
    sc = mfma16(qa0, kb0, sc);
    sc = mfma16(qa1, kb1, sc);

#pragma unroll
    for (int r = 0; r < 4; ++r) {
        float s = sc[r] * 0.125f;
        float mx = s;
#pragma unroll
        for (int off = 1; off < 16; off <<= 1) mx = fmaxf(mx, __shfl_xor(mx, off, 64));
        float e = __expf(s - mx);
        float sm = e;
#pragma unroll
        for (int off = 1; off < 16; off <<= 1) sm += __shfl_xor(sm, off, 64);
        lds_p[wave][(g * 4 + r) * 16 + nn] = f2bf(e / sm);
    }
    CFENCE;

    bf16x8 zero8 = {};
    bf16x8 pa = (g < 2) ? *(const bf16x8*)&lds_p[wave][nn * 16 + g * 8] : zero8;
#pragma unroll
    for (int dt = 0; dt < 4; ++dt) {
        bf16x8 vb = (g < 2) ? *(const bf16x8*)&vt[wave][(dt * 16 + nn) * 16 + g * 8] : zero8;
        f32x4 o = mfma16(pa, vb, (f32x4){0.f, 0.f, 0.f, 0.f});
#pragma unroll
        for (int r = 0; r < 4; ++r) {
            size_t orow = rowb + g * 4 + r;
            S[orow * 1024 + h * 64 + dt * 16 + nn] = f2bf(o[r]);
        }
    }
}

// ---------------- atrous attention: 4 waves/block, independent waves ------

__global__ __launch_bounds__(256) void attn_atrous(
    const ushort_t* __restrict__ Q, const ushort_t* __restrict__ K,
    const ushort_t* __restrict__ V,
    const float* __restrict__ bq, const float* __restrict__ bk,
    const float* __restrict__ bv, ushort_t* __restrict__ S)
{
    const int wave = threadIdx.x >> 6, lane = threadIdx.x & 63;
    const int unit = blockIdx.x * 4 + wave;
    const int h = unit & 15;
    const int tmp = unit >> 4;
    const int c = tmp % 86;
    const int sidx = tmp / 86;
    const int b = sidx / 3, dil = sidx % 3;
    const int g = lane >> 4, nn = lane & 15;
    __shared__ ushort_t lds_p[4][16 * 16];
    __shared__ ushort_t vt[4][64 * 16];

    const int dof = h * 64 + g * 8;
    const int p_n = 3 * (c * 16 + nn) + dil;
    bf16x8 qa0, qa1, kb0, kb1;
    if (p_n < 4096) {
        size_t o = ((size_t)b * 4096 + p_n) * 1024 + dof;
        qa0 = *(const bf16x8*)(Q + o);
        qa1 = *(const bf16x8*)(Q + o + 32);
        kb0 = *(const bf16x8*)(K + o);
        kb1 = *(const bf16x8*)(K + o + 32);
    } else {
        qa0 = bias8(bq, dof); qa1 = bias8(bq, dof + 32);
        kb0 = bias8(bk, dof); kb1 = bias8(bk, dof + 32);
    }

#pragma unroll
    for (int it = 0; it < 2; ++it) {
        int u = it * 64 + lane;
        int n = u >> 3, cc = u & 7;
        int p_v = 3 * (c * 16 + n) + dil;
        bf16x8 vv = (p_v < 4096)
            ? *(const bf16x8*)(V + ((size_t)b * 4096 + p_v) * 1024 + h * 64 + cc * 8)
            : bias8(bv, h * 64 + cc * 8);
        union { bf16x8 v; ushort_t u8[8]; } vu; vu.v = vv;
#pragma unroll
        for (int j = 0; j < 8; ++j) vt[wave][(cc * 8 + j) * 16 + n] = vu.u8[j];
    }

    f32x4 sc = {0.f, 0.f, 0.f, 0.f};
    sc = mfma16(qa0, kb0, sc);
    sc = mfma16(qa1, kb1, sc);

#pragma unroll
    for (int r = 0; r < 4; ++r) {
        float s = sc[r] * 0.125f;
        float mx = s;
#pragma unroll
        for (int off = 1; off < 16; off <<= 1) mx = fmaxf(mx, __shfl_xor(mx, off, 64));
        float e = __expf(s - mx);
        float sm = e;
#pragma unroll
        for (int off = 1; off < 16; off <<= 1) sm += __shfl_xor(sm, off, 64);
        lds_p[wave][(g * 4 + r) * 16 + nn] = f2bf(e / sm);
    }
    CFENCE;

    bf16x8 zero8 = {};
    bf16x8 pa = (g < 2) ? *(const bf16x8*)&lds_p[wave][nn * 16 + g * 8] : zero8;
#pragma unroll
    for (int dt = 0; dt < 4; ++dt) {
        bf16x8 vb = (g < 2) ? *(const bf16x8*)&vt[wave][(dt * 16 + nn) * 16 + g * 8] : zero8;
        f32x4 o = mfma16(pa, vb, (f32x4){0.f, 0.f, 0.f, 0.f});
#pragma unroll
        for (int r = 0; r < 4; ++r) {
            int p_q = 3 * (c * 16 + g * 4 + r) + dil;
            if (p_q < 4096) {
                size_t off = ((size_t)b * 4096 + p_q) * 1024 + h * 64 + dt * 16 + nn;
                S[off] = f2bf(bf2f(S[off]) + o[r]);
            }
        }
    }
}

// ---------------- launch ----------------

extern "C" void kernel_launch(void* const* d_in, const int* in_sizes, int n_in,
                              void* d_out, int out_size, void* d_ws, size_t ws_size,
                              hipStream_t stream)
{
    const float* x  = (const float*)d_in[0];
    const float* Wq = (const float*)d_in[1];
    const float* bq = (const float*)d_in[2];
    const float* Wk = (const float*)d_in[3];
    const float* bk = (const float*)d_in[4];
    const float* Wv = (const float*)d_in[5];
    const float* bv = (const float*)d_in[6];
    const float* Wo = (const float*)d_in[7];
    const float* bo = (const float*)d_in[8];
    float* out = (float*)d_out;

    const size_t NT = 16384;            // total tokens (4 * 4096)
    ushort_t* xb   = (ushort_t*)d_ws;                  // 16M bf16
    ushort_t* wqkv = xb + NT * 1024;                   // 3M bf16 (Wq|Wk|Wv rows)
    ushort_t* wo   = wqkv + 3 * 1024 * 1024;           // 1M bf16 (contiguous after wqkv)
    ushort_t* Qb   = wo + 1024 * 1024;                 // 16M bf16
    ushort_t* Kb   = Qb + NT * 1024;
    ushort_t* Vb   = Kb + NT * 1024;
    ushort_t* Sb   = Vb + NT * 1024;                   // local+atrous sum, bf16
    float*    bqkv = (float*)(Sb + NT * 1024);         // 3072 fp32

    // fused fp32 -> bf16 conversion + bias pack
    const int total_units = 2097152 + 4 * 131072 + 384;
    cvt_all<<<(total_units + 255) / 256, 256, 0, stream>>>(
        x, Wq, Wk, Wv, Wo, bq, bk, bv, xb, wqkv, bqkv);

    // fused QKV projection: (16384x1024) @ (3072x1024)^T ; grid 64*12=768 (%8==0)
    gemm6<0><<<768, 512, 0, stream>>>(xb, wqkv, bqkv, (void*)Qb, (int)NT, 12);

    // attention
    attn_local <<<4096, 256, 0, stream>>>(Qb, Kb, Vb, Sb);
    attn_atrous<<<4128, 256, 0, stream>>>(Qb, Kb, Vb, bq, bk, bv, Sb);

    // output projection: (16384x1024) @ (1024x1024)^T -> fp32 ; grid 64*4=256
    gemm6<1><<<256, 512, 0, stream>>>(Sb, wo, bo, (void*)out, (int)NT, 4);
}